// Round 4
// baseline (169.074 us; speedup 1.0000x reference)
//
#include <hip/hip_runtime.h>

typedef unsigned short u16;
typedef unsigned int u32;
typedef __attribute__((ext_vector_type(8))) short short8;
typedef __attribute__((ext_vector_type(4))) float f32x4;

#define T_ 4096

#if __has_builtin(__builtin_amdgcn_exp2f)
#define EXP2F(x) __builtin_amdgcn_exp2f(x)
#else
#define EXP2F(x) exp2f(x)
#endif

__device__ __forceinline__ u16 f2bf(float f) {
    unsigned u = __float_as_uint(f);
    u += 0x7FFFu + ((u >> 16) & 1u);   // RNE to bf16
    return (u16)(u >> 16);
}

// ---------------------------------------------------------------------------
// Kernel 0: W -> WTf in MFMA-B-fragment-contiguous order.
// frag (ng 0..11, kc 0..15): WTf[(ng*16+kc)*512 + lane*8 + j] =
//   W_{ng/4}[kc*32 + (lane>>4)*8 + j][(ng&3)*16 + (lane&15)]
// ---------------------------------------------------------------------------
__global__ __launch_bounds__(256) void wtrans_kernel(
    const float* __restrict__ Wq, const float* __restrict__ Wk,
    const float* __restrict__ Wv, u16* __restrict__ WTf)
{
    const int tid  = blockIdx.x * 256 + threadIdx.x;   // 48*256 = 12288
    const int frag = tid >> 6;                          // 0..191
    const int lane = tid & 63;
    const int ng   = frag >> 4;
    const int kc   = frag & 15;
    const int m    = ng >> 2;
    const float* W = (m == 0) ? Wq : (m == 1) ? Wk : Wv;
    const int h  = (ng & 3) * 16 + (lane & 15);
    const int c0 = kc * 32 + (lane >> 4) * 8;
    short8 v;
    #pragma unroll
    for (int j = 0; j < 8; ++j)
        v[j] = (short)f2bf(W[(c0 + j) * 64 + h]);
    *(short8*)(WTf + (size_t)frag * 512 + lane * 8) = v;
}

// ---------------------------------------------------------------------------
// Kernel 1: projection. 512 blocks x 32 rows; x staged to LDS bf16; B-frags
// are single dense 1KB loads from WTf. Epilogue scatters into Qf/Kf/Vf
// fragment-contiguous layouts consumed by attn.
// ---------------------------------------------------------------------------
__global__ __launch_bounds__(256) void proj_kernel(
    const float* __restrict__ x, const u16* __restrict__ WTf,
    u16* __restrict__ Qf, u16* __restrict__ Kf, u16* __restrict__ Vf)
{
    __shared__ u16 xs[32 * 520];
    const int lane = threadIdx.x & 63;
    const int w    = threadIdx.x >> 6;
    const int l16  = lane & 15;
    const int quad = lane >> 4;
    const int rowbase = blockIdx.x * 32;

    #pragma unroll
    for (int it = 0; it < 16; ++it) {
        int f   = threadIdx.x + it * 256;
        int row = f >> 7;
        int c4  = (f & 127) * 4;
        f32x4 a = *(const f32x4*)(x + (size_t)(rowbase + row) * 512 + c4);
        unsigned lo = (unsigned)f2bf(a[0]) | ((unsigned)f2bf(a[1]) << 16);
        unsigned hi = (unsigned)f2bf(a[2]) | ((unsigned)f2bf(a[3]) << 16);
        *(uint2*)(xs + row * 520 + c4) = make_uint2(lo, hi);
    }
    __syncthreads();

    f32x4 acc[2][3];
    #pragma unroll
    for (int g = 0; g < 2; ++g)
        for (int nt = 0; nt < 3; ++nt) acc[g][nt] = (f32x4){0.f, 0.f, 0.f, 0.f};

    const int ng0 = w * 3;
    const u16* a0 = xs + l16 * 520 + quad * 8;
    const u16* a1 = xs + (16 + l16) * 520 + quad * 8;
    const u16* wb = WTf + (size_t)(ng0 * 16) * 512 + lane * 8;

    #pragma unroll 4
    for (int kc = 0; kc < 16; ++kc) {
        short8 af0 = *(const short8*)(a0 + kc * 32);
        short8 af1 = *(const short8*)(a1 + kc * 32);
        #pragma unroll
        for (int nt = 0; nt < 3; ++nt) {
            short8 bf = *(const short8*)(wb + (size_t)(nt * 16 + kc) * 512);
            acc[0][nt] = __builtin_amdgcn_mfma_f32_16x16x32_bf16(af0, bf, acc[0][nt], 0, 0, 0);
            acc[1][nt] = __builtin_amdgcn_mfma_f32_16x16x32_bf16(af1, bf, acc[1][nt], 0, 0, 0);
        }
    }

    const int bat  = rowbase >> 12;
    const int tloc = rowbase & 4095;
    #pragma unroll
    for (int g = 0; g < 2; ++g) {
        #pragma unroll
        for (int nt = 0; nt < 3; ++nt) {
            int ng = ng0 + nt;
            if (ng < 8) {
                // Q/K fragment layout: [((bat*256+tb)*2+f)*512 + quadK*128 + m16*8 + jj]
                u16* base = (ng < 4) ? Qf : Kf;
                int ng4   = ng & 3;
                int f     = ng4 >> 1;
                int quadK = (ng4 & 1) * 2 + (l16 >> 3);
                int jj    = l16 & 7;
                int tb    = (tloc >> 4) + g;
                u16* dst  = base + ((size_t)((bat * 256 + tb) * 2 + f)) * 512
                                 + quadK * 128 + jj;
                #pragma unroll
                for (int i = 0; i < 4; ++i)
                    dst[(quad * 4 + i) * 8] = f2bf(acc[g][nt][i]);
            } else {
                // V fragment: [(((bat*32+kt)*4+ks)*4+nt2)*512 + quadV*128 + l16*8 + jv]
                int nt2   = ng - 8;
                int kt    = tloc >> 7;
                int ks    = (tloc >> 5) & 3;
                int quadV = 2 * g + (quad >> 1);
                int jv4   = (quad & 1) * 4;
                unsigned lo = (unsigned)f2bf(acc[g][nt][0]) | ((unsigned)f2bf(acc[g][nt][1]) << 16);
                unsigned hi = (unsigned)f2bf(acc[g][nt][2]) | ((unsigned)f2bf(acc[g][nt][3]) << 16);
                u16* dst = Vf + ((size_t)(((bat * 32 + kt) * 4 + ks) * 4 + nt2)) * 512
                              + quadV * 128 + l16 * 8 + jv4;
                *(uint2*)dst = make_uint2(lo, hi);
            }
        }
    }
}

// ---------------------------------------------------------------------------
// Kernel 2: LDS-free, barrier-free K-split attention. One WAVE per task
// (bat = wave-in-block, q32 tile, chunk of CH key tiles). All loads are
// dense 1KB fragment loads. Computes S^T = K*Q^T; P^T fragments built via
// in-register quad permutation (shfl); O^T accumulated; partials (bf16-
// packed num, f32 den) stored to deterministic slots; fin reduces.
// ---------------------------------------------------------------------------
__global__ __launch_bounds__(256, 4) void attn_kernel(
    const u16* __restrict__ Qf, const u16* __restrict__ Kf,
    const u16* __restrict__ Vf, u32* __restrict__ pnum,
    float* __restrict__ pden, int CH, int S_bat)
{
    const int w    = threadIdx.x >> 6;
    const int lane = threadIdx.x & 63;
    const int l16  = lane & 15;
    const int qd   = lane >> 4;
    const int bat  = w;
    const int s    = blockIdx.x;

    int A = 31, pre = 0, cc = 1;
    for (;;) {
        cc = (A + CH) / CH;
        int cnt = 4 * cc;
        if (s < pre + cnt) break;
        pre += cnt; --A;
    }
    const int r    = s - pre;
    const int b_   = r / cc;
    const int c    = r - b_ * cc;
    const int nkt  = A + 1;
    const int q32  = 4 * A + b_;
    const int kt0  = c * CH;
    const int kt1  = min(kt0 + CH, nkt);
    const int slot = bat * S_bat + pre + b_ * cc + c;

    // Q fragments (dense 1KB loads each)
    short8 aq[2][2];
    #pragma unroll
    for (int g = 0; g < 2; ++g)
        #pragma unroll
        for (int f = 0; f < 2; ++f)
            aq[g][f] = *(const short8*)(Qf
                + ((size_t)((bat * 256 + q32 * 2 + g) * 2 + f)) * 512 + lane * 8);

    f32x4 acc[2][4];
    float den[2] = {0.f, 0.f};
    #pragma unroll
    for (int g = 0; g < 2; ++g)
        for (int n = 0; n < 4; ++n) acc[g][n] = (f32x4){0.f, 0.f, 0.f, 0.f};

    for (int kt = kt0; kt < kt1; ++kt) {
        const u16* kfb = Kf + ((size_t)(bat * 256 + kt * 8) * 2) * 512 + lane * 8;
        const u16* vfb = Vf + ((size_t)((bat * 32 + kt) * 16)) * 512 + lane * 8;
        #pragma unroll
        for (int ks = 0; ks < 4; ++ks) {
            u32 pk[2][2][2];   // [b(nt-half)][g][h]
            #pragma unroll
            for (int b = 0; b < 2; ++b) {
                int nt = 2 * ks + b;
                short8 k0 = *(const short8*)(kfb + (size_t)nt * 1024);
                short8 k1 = *(const short8*)(kfb + (size_t)nt * 1024 + 512);
                #pragma unroll
                for (int g = 0; g < 2; ++g) {
                    f32x4 st = (f32x4){0.f, 0.f, 0.f, 0.f};
                    st = __builtin_amdgcn_mfma_f32_16x16x32_bf16(k0, aq[g][0], st, 0, 0, 0);
                    st = __builtin_amdgcn_mfma_f32_16x16x32_bf16(k1, aq[g][1], st, 0, 0, 0);
                    float p0 = EXP2F(st[0] * 0.18033688f);
                    float p1 = EXP2F(st[1] * 0.18033688f);
                    float p2 = EXP2F(st[2] * 0.18033688f);
                    float p3 = EXP2F(st[3] * 0.18033688f);
                    den[g] += (p0 + p1) + (p2 + p3);
                    pk[b][g][0] = (u32)f2bf(p0) | ((u32)f2bf(p1) << 16);
                    pk[b][g][1] = (u32)f2bf(p2) | ((u32)f2bf(p3) << 16);
                }
            }
            // build P^T B-fragments: quad permutation via shfl + select
            short8 ap[2];
            #pragma unroll
            for (int g = 0; g < 2; ++g) {
                u32 av[4];
                #pragma unroll
                for (int d = 0; d < 4; ++d) {
                    int h  = d & 1;
                    int qs = (qd & 1) * 2 + (d >> 1);
                    int sl = qs * 16 + l16;
                    int t0 = __shfl((int)pk[0][g][h], sl);
                    int t1 = __shfl((int)pk[1][g][h], sl);
                    av[d] = (qd < 2) ? (u32)t0 : (u32)t1;
                }
                union { u32 u[4]; short8 s8; } cv;
                cv.u[0] = av[0]; cv.u[1] = av[1]; cv.u[2] = av[2]; cv.u[3] = av[3];
                ap[g] = cv.s8;
            }
            // O^T += V^T * P^T
            #pragma unroll
            for (int nt2 = 0; nt2 < 4; ++nt2) {
                short8 av = *(const short8*)(vfb + (size_t)(ks * 4 + nt2) * 512);
                acc[0][nt2] = __builtin_amdgcn_mfma_f32_16x16x32_bf16(av, ap[0], acc[0][nt2], 0, 0, 0);
                acc[1][nt2] = __builtin_amdgcn_mfma_f32_16x16x32_bf16(av, ap[1], acc[1][nt2], 0, 0, 0);
            }
        }
    }

    // flush num (bf16-packed): num[slot][m 0..31][hpair 0..31] u32
    u32* np = pnum + (size_t)slot * 1024;
    #pragma unroll
    for (int g = 0; g < 2; ++g)
        #pragma unroll
        for (int nt2 = 0; nt2 < 4; ++nt2) {
            unsigned lo = (u32)f2bf(acc[g][nt2][0]) | ((u32)f2bf(acc[g][nt2][1]) << 16);
            unsigned hi = (u32)f2bf(acc[g][nt2][2]) | ((u32)f2bf(acc[g][nt2][3]) << 16);
            *(uint2*)(np + (g * 16 + l16) * 32 + nt2 * 8 + qd * 2) = make_uint2(lo, hi);
        }
    // den: reduce across the 4 quads (s-slices); lane l16 owns row m=l16 (+16g)
    #pragma unroll
    for (int g = 0; g < 2; ++g) {
        float d = den[g];
        d += __shfl_xor(d, 16);
        d += __shfl_xor(d, 32);
        if (lane < 16)
            pden[(size_t)slot * 32 + g * 16 + l16] = d;
    }
}

// ---------------------------------------------------------------------------
// Kernel 3: finalize — sum bf16-packed partial slots, divide, write out.
// ---------------------------------------------------------------------------
__global__ __launch_bounds__(256) void fin_kernel(
    const u32* __restrict__ pnum, const float* __restrict__ pden,
    float* __restrict__ out, int CH, int S_bat)
{
    __shared__ float rden[32];
    const int bq  = blockIdx.x;            // bat*128 + q32
    const int bat = bq >> 7;
    const int q32 = bq & 127;
    const int A = q32 >> 2, b = q32 & 3;
    int pre = 0;
    for (int j = 31; j > A; --j) pre += 4 * ((j + CH) / CH);
    const int cc   = (A + CH) / CH;
    const int base = bat * S_bat + pre + b * cc;

    if (threadIdx.x < 32) {
        float d = 0.f;
        for (int ci = 0; ci < cc; ++ci)
            d += pden[(size_t)(base + ci) * 32 + threadIdx.x];
        rden[threadIdx.x] = 1.0f / d;
    }
    __syncthreads();

    const int m  = threadIdx.x >> 3;        // 0..31
    const int hp = (threadIdx.x & 7) * 4;   // u32 col base
    float sv[8];
    #pragma unroll
    for (int e = 0; e < 8; ++e) sv[e] = 0.f;
    for (int ci = 0; ci < cc; ++ci) {
        const uint4 u = *(const uint4*)(pnum + (size_t)(base + ci) * 1024 + m * 32 + hp);
        const u32 uu[4] = {u.x, u.y, u.z, u.w};
        #pragma unroll
        for (int e = 0; e < 4; ++e) {
            sv[2 * e]     += __uint_as_float(uu[e] << 16);
            sv[2 * e + 1] += __uint_as_float(uu[e] & 0xFFFF0000u);
        }
    }
    const float rd = rden[m];
    float* op = out + (size_t)(bat * T_ + q32 * 32 + m) * 64 + (threadIdx.x & 7) * 8;
    f32x4 r0, r1;
    #pragma unroll
    for (int i = 0; i < 4; ++i) { r0[i] = sv[i] * rd; r1[i] = sv[4 + i] * rd; }
    *(f32x4*)(op)     = r0;
    *(f32x4*)(op + 4) = r1;
}

// ---------------------------------------------------------------------------
extern "C" void kernel_launch(void* const* d_in, const int* in_sizes, int n_in,
                              void* d_out, int out_size, void* d_ws, size_t ws_size,
                              hipStream_t stream)
{
    const float* x  = (const float*)d_in[0];
    const float* Wk = (const float*)d_in[1];
    const float* Wq = (const float*)d_in[2];
    const float* Wv = (const float*)d_in[3];
    float* out = (float*)d_out;

    u16* ws  = (u16*)d_ws;
    u16* WTf = ws;                          // 98304 u16
    u16* Qf  = ws + 131072;                 // 1048576 u16 each
    u16* Kf  = Qf + 1048576;
    u16* Vf  = Kf + 1048576;
    const size_t core_elems = 131072 + 3 * 1048576;

    auto Sof = [](int CH) { int S = 0; for (int A = 0; A < 32; ++A) S += 4 * ((A + CH) / CH); return S; };
    int CH = 2, S = Sof(2);                 // 1088 tasks/bat
    size_t need = core_elems * 2 + (size_t)4 * S * (1024 * 4 + 32 * 4);
    if (ws_size < need) { CH = 4; S = Sof(4); need = core_elems * 2 + (size_t)4 * S * (1024 * 4 + 32 * 4); }
    if (ws_size < need) { CH = 8; S = Sof(8); }
    u32*   pnum = (u32*)(ws + core_elems);
    float* pden = (float*)(pnum + (size_t)4 * S * 1024);

    wtrans_kernel<<<48, 256, 0, stream>>>(Wq, Wk, Wv, WTf);
    proj_kernel<<<512, 256, 0, stream>>>(x, WTf, Qf, Kf, Vf);
    attn_kernel<<<S, 256, 0, stream>>>(Qf, Kf, Vf, pnum, pden, CH, S);
    fin_kernel<<<512, 256, 0, stream>>>(pnum, pden, out, CH, S);
}

// Round 5
// 130.905 us; speedup vs baseline: 1.2916x; 1.2916x over previous
//
#include <hip/hip_runtime.h>

typedef unsigned short u16;
typedef unsigned int u32;
typedef unsigned long long u64;
typedef __attribute__((ext_vector_type(8))) short short8;
typedef __attribute__((ext_vector_type(4))) float f32x4;

#define T_ 4096

#if __has_builtin(__builtin_amdgcn_exp2f)
#define EXP2F(x) __builtin_amdgcn_exp2f(x)
#else
#define EXP2F(x) exp2f(x)
#endif

__device__ __forceinline__ u16 f2bf(float f) {
    unsigned u = __float_as_uint(f);
    u += 0x7FFFu + ((u >> 16) & 1u);   // RNE to bf16
    return (u16)(u >> 16);
}

// ---------------------------------------------------------------------------
// Kernel 0: W -> WTf in MFMA-B-fragment-contiguous order.
// ---------------------------------------------------------------------------
__global__ __launch_bounds__(256) void wtrans_kernel(
    const float* __restrict__ Wq, const float* __restrict__ Wk,
    const float* __restrict__ Wv, u16* __restrict__ WTf)
{
    const int tid  = blockIdx.x * 256 + threadIdx.x;   // 48*256 = 12288
    const int frag = tid >> 6;                          // 0..191
    const int lane = tid & 63;
    const int ng   = frag >> 4;
    const int kc   = frag & 15;
    const int m    = ng >> 2;
    const float* W = (m == 0) ? Wq : (m == 1) ? Wk : Wv;
    const int h  = (ng & 3) * 16 + (lane & 15);
    const int c0 = kc * 32 + (lane >> 4) * 8;
    short8 v;
    #pragma unroll
    for (int j = 0; j < 8; ++j)
        v[j] = (short)f2bf(W[(c0 + j) * 64 + h]);
    *(short8*)(WTf + (size_t)frag * 512 + lane * 8) = v;
}

// ---------------------------------------------------------------------------
// Kernel 1: projection. 512 blocks x 32 rows. Epilogue: scatter acc -> LDS
// image (bf16), then fully-coalesced b128 copy-out to Qf/Kf/Vf.
// ---------------------------------------------------------------------------
__global__ __launch_bounds__(256) void proj_kernel(
    const float* __restrict__ x, const u16* __restrict__ WTf,
    u16* __restrict__ Qf, u16* __restrict__ Kf, u16* __restrict__ Vf)
{
    __shared__ u16 xs[32 * 520];
    const int lane = threadIdx.x & 63;
    const int w    = threadIdx.x >> 6;
    const int l16  = lane & 15;
    const int quad = lane >> 4;
    const int rowbase = blockIdx.x * 32;

    #pragma unroll
    for (int it = 0; it < 16; ++it) {
        int f   = threadIdx.x + it * 256;
        int row = f >> 7;
        int c4  = (f & 127) * 4;
        f32x4 a = *(const f32x4*)(x + (size_t)(rowbase + row) * 512 + c4);
        unsigned lo = (unsigned)f2bf(a[0]) | ((unsigned)f2bf(a[1]) << 16);
        unsigned hi = (unsigned)f2bf(a[2]) | ((unsigned)f2bf(a[3]) << 16);
        *(uint2*)(xs + row * 520 + c4) = make_uint2(lo, hi);
    }
    __syncthreads();

    f32x4 acc[2][3];
    #pragma unroll
    for (int g = 0; g < 2; ++g)
        for (int nt = 0; nt < 3; ++nt) acc[g][nt] = (f32x4){0.f, 0.f, 0.f, 0.f};

    const int ng0 = w * 3;
    const u16* a0 = xs + l16 * 520 + quad * 8;
    const u16* a1 = xs + (16 + l16) * 520 + quad * 8;
    const u16* wb = WTf + (size_t)(ng0 * 16) * 512 + lane * 8;

    #pragma unroll 4
    for (int kc = 0; kc < 16; ++kc) {
        short8 af0 = *(const short8*)(a0 + kc * 32);
        short8 af1 = *(const short8*)(a1 + kc * 32);
        #pragma unroll
        for (int nt = 0; nt < 3; ++nt) {
            short8 bf = *(const short8*)(wb + (size_t)(nt * 16 + kc) * 512);
            acc[0][nt] = __builtin_amdgcn_mfma_f32_16x16x32_bf16(af0, bf, acc[0][nt], 0, 0, 0);
            acc[1][nt] = __builtin_amdgcn_mfma_f32_16x16x32_bf16(af1, bf, acc[1][nt], 0, 0, 0);
        }
    }

    // ---- epilogue: LDS image (imgQ @0, imgK @2048, imgV @4096; u16 units) ----
    __syncthreads();   // done reading xs
    #pragma unroll
    for (int g = 0; g < 2; ++g) {
        #pragma unroll
        for (int nt = 0; nt < 3; ++nt) {
            int ng = ng0 + nt;
            if (ng < 8) {
                int ng4 = ng & 3;
                u16* ib = xs + ((ng < 4) ? 0 : 2048) + g * 1024 + (ng4 >> 1) * 512
                             + ((ng4 & 1) * 2 + (l16 >> 3)) * 128 + (l16 & 7);
                #pragma unroll
                for (int i = 0; i < 4; ++i)
                    ib[(quad * 4 + i) * 8] = f2bf(acc[g][nt][i]);
            } else {
                int nt2   = ng - 8;
                int quadV = 2 * g + (quad >> 1);
                int jv4   = (quad & 1) * 4;
                unsigned lo = (unsigned)f2bf(acc[g][nt][0]) | ((unsigned)f2bf(acc[g][nt][1]) << 16);
                unsigned hi = (unsigned)f2bf(acc[g][nt][2]) | ((unsigned)f2bf(acc[g][nt][3]) << 16);
                *(uint2*)(xs + 4096 + nt2 * 512 + quadV * 128 + l16 * 8 + jv4) = make_uint2(lo, hi);
            }
        }
    }
    __syncthreads();
    // coalesced copy-out: 3 contiguous 4KB spans
    const int t   = threadIdx.x;
    const int bat = rowbase >> 12;
    const int tloc = rowbase & 4095;
    const int tb0 = tloc >> 4;
    const int kt  = tloc >> 7;
    const int ks  = (tloc >> 5) & 3;
    short8 vq = *(short8*)(xs + t * 8);
    short8 vk = *(short8*)(xs + 2048 + t * 8);
    short8 vv = *(short8*)(xs + 4096 + t * 8);
    *(short8*)(Qf + (size_t)(bat * 256 + tb0) * 1024 + t * 8) = vq;
    *(short8*)(Kf + (size_t)(bat * 256 + tb0) * 1024 + t * 8) = vk;
    *(short8*)(Vf + (size_t)((bat * 32 + kt) * 4 + ks) * 2048 + t * 8) = vv;
}

// ---------------------------------------------------------------------------
// Kernel 2: XCD-pinned, LDS-free, barrier-free K-split attention.
// bat = (bid&7)>>1 so each XCD touches one batch (1.5 MB, L2-resident).
// Within a block the 4 waves share one key-chunk (b fastest) -> L1 reuse.
// Partials: nt u64 stores (dense), deterministic slots; fin reduces.
// ---------------------------------------------------------------------------
__global__ __launch_bounds__(256, 4) void attn_kernel(
    const u16* __restrict__ Qf, const u16* __restrict__ Kf,
    const u16* __restrict__ Vf, u32* __restrict__ pnum,
    float* __restrict__ pden, int CH, int S_bat)
{
    const int w    = threadIdx.x >> 6;
    const int lane = threadIdx.x & 63;
    const int l16  = lane & 15;
    const int qd   = lane >> 4;
    const int xcd  = blockIdx.x & 7;
    const int bat  = xcd >> 1;
    const int tw   = ((blockIdx.x >> 3) * 2 + (xcd & 1)) * 4 + w;  // 0..S_bat-1

    int A = 31, pre = 0, cc = 1;
    for (;;) {                               // big-A first
        cc = (A + CH) / CH;
        int cnt = 4 * cc;
        if (tw < pre + cnt) break;
        pre += cnt; --A;
    }
    const int r    = tw - pre;
    const int c    = r >> 2;                 // chunk: shared by the 4 waves
    const int b_   = r & 3;
    const int nkt  = A + 1;
    const int q32  = 4 * A + b_;
    const int kt0  = c * CH;
    const int kt1  = min(kt0 + CH, nkt);
    const int slot = bat * S_bat + tw;

    short8 aq[2][2];
    #pragma unroll
    for (int g = 0; g < 2; ++g)
        #pragma unroll
        for (int f = 0; f < 2; ++f)
            aq[g][f] = *(const short8*)(Qf
                + ((size_t)((bat * 256 + q32 * 2 + g) * 2 + f)) * 512 + lane * 8);

    f32x4 acc[2][4];
    float den[2] = {0.f, 0.f};
    #pragma unroll
    for (int g = 0; g < 2; ++g)
        for (int n = 0; n < 4; ++n) acc[g][n] = (f32x4){0.f, 0.f, 0.f, 0.f};

    for (int kt = kt0; kt < kt1; ++kt) {
        const u16* kfb = Kf + ((size_t)(bat * 256 + kt * 8) * 2) * 512 + lane * 8;
        const u16* vfb = Vf + ((size_t)((bat * 32 + kt) * 16)) * 512 + lane * 8;
        #pragma unroll
        for (int ks = 0; ks < 4; ++ks) {
            u32 pk[2][2][2];   // [b(nt-half)][g][h]
            #pragma unroll
            for (int b = 0; b < 2; ++b) {
                int nt = 2 * ks + b;
                short8 k0 = *(const short8*)(kfb + (size_t)nt * 1024);
                short8 k1 = *(const short8*)(kfb + (size_t)nt * 1024 + 512);
                #pragma unroll
                for (int g = 0; g < 2; ++g) {
                    f32x4 st = (f32x4){0.f, 0.f, 0.f, 0.f};
                    st = __builtin_amdgcn_mfma_f32_16x16x32_bf16(k0, aq[g][0], st, 0, 0, 0);
                    st = __builtin_amdgcn_mfma_f32_16x16x32_bf16(k1, aq[g][1], st, 0, 0, 0);
                    float p0 = EXP2F(st[0] * 0.18033688f);
                    float p1 = EXP2F(st[1] * 0.18033688f);
                    float p2 = EXP2F(st[2] * 0.18033688f);
                    float p3 = EXP2F(st[3] * 0.18033688f);
                    // truncate to bf16 via v_perm; den sums the SAME truncated vals
                    u32 q01 = __builtin_amdgcn_perm(__float_as_uint(p1), __float_as_uint(p0), 0x07060302u);
                    u32 q23 = __builtin_amdgcn_perm(__float_as_uint(p3), __float_as_uint(p2), 0x07060302u);
                    den[g] += __uint_as_float(q01 << 16) + __uint_as_float(q01 & 0xffff0000u)
                            + __uint_as_float(q23 << 16) + __uint_as_float(q23 & 0xffff0000u);
                    pk[b][g][0] = q01;
                    pk[b][g][1] = q23;
                }
            }
            short8 ap[2];
            #pragma unroll
            for (int g = 0; g < 2; ++g) {
                u32 av[4];
                #pragma unroll
                for (int d = 0; d < 4; ++d) {
                    int h  = d & 1;
                    int qs = (qd & 1) * 2 + (d >> 1);
                    int sl = qs * 16 + l16;
                    int t0 = __shfl((int)pk[0][g][h], sl);
                    int t1 = __shfl((int)pk[1][g][h], sl);
                    av[d] = (qd < 2) ? (u32)t0 : (u32)t1;
                }
                union { u32 u[4]; short8 s8; } cv;
                cv.u[0] = av[0]; cv.u[1] = av[1]; cv.u[2] = av[2]; cv.u[3] = av[3];
                ap[g] = cv.s8;
            }
            #pragma unroll
            for (int nt2 = 0; nt2 < 4; ++nt2) {
                short8 av = *(const short8*)(vfb + (size_t)(ks * 4 + nt2) * 512);
                acc[0][nt2] = __builtin_amdgcn_mfma_f32_16x16x32_bf16(av, ap[0], acc[0][nt2], 0, 0, 0);
                acc[1][nt2] = __builtin_amdgcn_mfma_f32_16x16x32_bf16(av, ap[1], acc[1][nt2], 0, 0, 0);
            }
        }
    }

    // flush: dense nt u64 stores. pnum u32 idx = (g*4+nt2)*128 + lane*2 + pr
    u32* np = pnum + (size_t)slot * 1024;
    #pragma unroll
    for (int g = 0; g < 2; ++g)
        #pragma unroll
        for (int nt2 = 0; nt2 < 4; ++nt2) {
            u32 lo = (u32)f2bf(acc[g][nt2][0]) | ((u32)f2bf(acc[g][nt2][1]) << 16);
            u32 hi = (u32)f2bf(acc[g][nt2][2]) | ((u32)f2bf(acc[g][nt2][3]) << 16);
            u64 val = (u64)lo | ((u64)hi << 32);
            __builtin_nontemporal_store(val, (u64*)(np + (g * 4 + nt2) * 128 + lane * 2));
        }
    #pragma unroll
    for (int g = 0; g < 2; ++g) {
        float d = den[g];
        d += __shfl_xor(d, 16);
        d += __shfl_xor(d, 32);
        if (lane < 16)
            __builtin_nontemporal_store(d, &pden[(size_t)slot * 32 + g * 16 + l16]);
    }
}

// ---------------------------------------------------------------------------
// Kernel 3: finalize — sum partial slots (chunk stride 4 in slot space),
// divide, write out.
// ---------------------------------------------------------------------------
__global__ __launch_bounds__(256) void fin_kernel(
    const u32* __restrict__ pnum, const float* __restrict__ pden,
    float* __restrict__ out, int CH, int S_bat)
{
    __shared__ float rden[32];
    const int bq  = blockIdx.x;            // bat*128 + q32
    const int bat = bq >> 7;
    const int q32 = bq & 127;
    const int A = q32 >> 2, b = q32 & 3;
    int pre = 0;
    for (int j = 31; j > A; --j) pre += 4 * ((j + CH) / CH);
    const int cc   = (A + CH) / CH;
    const int base = bat * S_bat + pre + b;   // chunk ci at base + 4*ci

    if (threadIdx.x < 32) {
        float d = 0.f;
        for (int ci = 0; ci < cc; ++ci)
            d += pden[(size_t)(base + 4 * ci) * 32 + threadIdx.x];
        rden[threadIdx.x] = 1.0f / d;
    }
    __syncthreads();

    const int m   = threadIdx.x >> 3;       // out row 0..31
    const int g   = m >> 4;
    const int l16 = m & 15;
    const int h0  = (threadIdx.x & 7) * 8;
    const int nt2 = h0 >> 4;
    const int q0  = (h0 >> 2) & 3;
    const int off = (g * 4 + nt2) * 128 + q0 * 32 + l16 * 2;

    float sv[8];
    #pragma unroll
    for (int e = 0; e < 8; ++e) sv[e] = 0.f;
    for (int ci = 0; ci < cc; ++ci) {
        const u32* sp = pnum + (size_t)(base + 4 * ci) * 1024 + off;
        uint2 a  = *(const uint2*)(sp);
        uint2 bb = *(const uint2*)(sp + 32);
        u32 vals[4] = {a.x, a.y, bb.x, bb.y};
        #pragma unroll
        for (int e = 0; e < 4; ++e) {
            sv[2 * e]     += __uint_as_float(vals[e] << 16);
            sv[2 * e + 1] += __uint_as_float(vals[e] & 0xFFFF0000u);
        }
    }
    const float rd = rden[m];
    float* op = out + (size_t)(bat * T_ + q32 * 32 + m) * 64 + h0;
    f32x4 r0, r1;
    #pragma unroll
    for (int i = 0; i < 4; ++i) { r0[i] = sv[i] * rd; r1[i] = sv[4 + i] * rd; }
    *(f32x4*)(op)     = r0;
    *(f32x4*)(op + 4) = r1;
}

// ---------------------------------------------------------------------------
extern "C" void kernel_launch(void* const* d_in, const int* in_sizes, int n_in,
                              void* d_out, int out_size, void* d_ws, size_t ws_size,
                              hipStream_t stream)
{
    const float* x  = (const float*)d_in[0];
    const float* Wk = (const float*)d_in[1];
    const float* Wq = (const float*)d_in[2];
    const float* Wv = (const float*)d_in[3];
    float* out = (float*)d_out;

    u16* ws  = (u16*)d_ws;
    u16* WTf = ws;                          // 98304 u16
    u16* Qf  = ws + 131072;                 // 1048576 u16 each
    u16* Kf  = Qf + 1048576;
    u16* Vf  = Kf + 1048576;
    const size_t core_elems = 131072 + 3 * 1048576;

    auto Sof = [](int CH) { int S = 0; for (int A = 0; A < 32; ++A) S += 4 * ((A + CH) / CH); return S; };
    int CH = 2, S = Sof(2);                 // 1088 wave-tasks/bat, %8==0
    size_t need = core_elems * 2 + (size_t)4 * S * (1024 * 4 + 32 * 4);
    if (ws_size < need) { CH = 4; S = Sof(4); need = core_elems * 2 + (size_t)4 * S * (1024 * 4 + 32 * 4); }
    if (ws_size < need) { CH = 8; S = Sof(8); }
    u32*   pnum = (u32*)(ws + core_elems);
    float* pden = (float*)(pnum + (size_t)4 * S * 1024);

    wtrans_kernel<<<48, 256, 0, stream>>>(Wq, Wk, Wv, WTf);
    proj_kernel<<<512, 256, 0, stream>>>(x, WTf, Qf, Kf, Vf);
    attn_kernel<<<S, 256, 0, stream>>>(Qf, Kf, Vf, pnum, pden, CH, S);
    fin_kernel<<<512, 256, 0, stream>>>(pnum, pden, out, CH, S);
}